// Round 10
// baseline (70.900 us; speedup 1.0000x reference)
//
#include <hip/hip_runtime.h>

// 8-qubit VQC — closed-form evaluation (math validated R7-R9), single kernel.
// <Z_q> = Π_{p∈S_q} cos x_p · Σ_b tab_q[b] Π_{p∈V_q\S_q} (1+(-1)^{b_p} sin x_p)
// tab_q[b] = 2^{-|V_q|} Σ_{S-bits} cos Δ_q  (116 floats, weights-only; static
// per-q template descriptors -> all immediates, computed per block into LDS).
// R10 change vs R9: expansion levels folded into the dot products —
// DOT(EXPAND(src,n,P)) = Σ src[i]·(ap[P]·tab[o+i] + bm[P]·tab[o+n+i]);
// G5 folds two levels. Only o2/o4/o8/e2/e4/e8 materialized (28 regs), ~250
// instr/thread vs ~450, no spill risk (__launch_bounds__(256,8)).

template<int Q> struct QD;
template<> struct QD<0> { static constexpr int NB=2,NS=1,NA=2;
  static constexpr int vms[2]={1,2}; static constexpr int vis[1]={0};
  static constexpr int mask[2]={3,5}; static constexpr int aidx[2]={0,8}; };
template<> struct QD<1> { static constexpr int NB=3,NS=1,NA=3;
  static constexpr int vms[3]={0,2,3}; static constexpr int vis[1]={1};
  static constexpr int mask[3]={3,6,10}; static constexpr int aidx[3]={0,1,9}; };
template<> struct QD<2> { static constexpr int NB=3,NS=2,NA=4;
  static constexpr int vms[3]={1,3,4}; static constexpr int vis[2]={0,2};
  static constexpr int mask[4]={3,6,12,20}; static constexpr int aidx[4]={0,1,2,10}; };
template<> struct QD<3> { static constexpr int NB=4,NS=2,NA=5;
  static constexpr int vms[4]={0,2,4,5}; static constexpr int vis[2]={1,3};
  static constexpr int mask[5]={3,6,12,24,40}; static constexpr int aidx[5]={0,1,2,3,11}; };
template<> struct QD<4> { static constexpr int NB=4,NS=3,NA=6;
  static constexpr int vms[4]={1,3,5,6}; static constexpr int vis[3]={0,2,4};
  static constexpr int mask[6]={3,6,12,24,48,80}; static constexpr int aidx[6]={0,1,2,3,4,12}; };
template<> struct QD<5> { static constexpr int NB=5,NS=3,NA=7;
  static constexpr int vms[5]={0,2,4,6,7}; static constexpr int vis[3]={1,3,5};
  static constexpr int mask[7]={3,6,12,24,48,96,160}; static constexpr int aidx[7]={0,1,2,3,4,5,13}; };
template<> struct QD<6> { static constexpr int NB=4,NS=4,NA=8;
  static constexpr int vms[4]={1,3,5,7}; static constexpr int vis[4]={0,2,4,6};
  static constexpr int mask[8]={3,6,12,24,48,96,192,64}; static constexpr int aidx[8]={0,1,2,3,4,5,6,14}; };
template<> struct QD<7> { static constexpr int NB=4,NS=4,NA=9;
  static constexpr int vms[4]={0,2,4,6}; static constexpr int vis[4]={1,3,5,7};
  static constexpr int mask[9]={3,6,12,24,48,96,192,128,128}; static constexpr int aidx[9]={0,1,2,3,4,5,6,7,15}; };

template<int Q>
__device__ __forceinline__ float table_entry(int b, const float* wv) {
    using D = QD<Q>;
    int ybase = 0;
#pragma unroll
    for (int k = 0; k < D::NB; ++k) ybase |= ((b >> k) & 1) << D::vms[k];
    float acc = 0.0f;
#pragma unroll
    for (int ys = 0; ys < (1 << D::NS); ++ys) {
        int y = ybase;
#pragma unroll
        for (int k = 0; k < D::NS; ++k) y |= ((ys >> k) & 1) << D::vis[k];
        float d = 0.0f;
#pragma unroll
        for (int j = 0; j < D::NA; ++j)
            d += (__popc(y & D::mask[j]) & 1) ? -wv[D::aidx[j]] : wv[D::aidx[j]];
        acc += __cosf(d);
    }
    return acc * (1.0f / (float)(1 << (D::NS + D::NB)));
}

__global__ __launch_bounds__(256, 8) void vqc_kernel(
    const float* __restrict__ inputs,   // (B, 8)
    const float* __restrict__ weights,  // (2, 8)
    float* __restrict__ out)            // (B, 8)
{
    __shared__ float tab[116];
    const int t = threadIdx.x;

    // ---- phase 1: weights-only table into LDS (threads 0..115, all static) ----
    if (t < 116) {
        float wv[16];
#pragma unroll
        for (int j = 0; j < 16; ++j) wv[j] = weights[j];
        float val;
        if      (t <   4) val = table_entry<0>(t,       wv);
        else if (t <  12) val = table_entry<1>(t -   4, wv);
        else if (t <  20) val = table_entry<2>(t -  12, wv);
        else if (t <  36) val = table_entry<3>(t -  20, wv);
        else if (t <  52) val = table_entry<4>(t -  36, wv);
        else if (t <  84) val = table_entry<5>(t -  52, wv);
        else if (t < 100) val = table_entry<6>(t -  84, wv);
        else              val = table_entry<7>(t - 100, wv);
        tab[t] = val;
    }
    __syncthreads();

    // ---- phase 2: per-element closed form, expansions folded into dots ----
    const int e = blockIdx.x * 256 + t;

    const float4* i4 = (const float4*)inputs + (size_t)e * 2;
    const float4 A = i4[0], Bv = i4[1];
    const float x[8] = {A.x, A.y, A.z, A.w, Bv.x, Bv.y, Bv.z, Bv.w};

    float s[8], c[8], ap[8], bm[8];
#pragma unroll
    for (int p = 0; p < 8; ++p) {
        s[p] = __sinf(x[p]);
        c[p] = __cosf(x[p]);
        ap[p] = 1.0f + s[p];
        bm[p] = 1.0f - s[p];
    }

    // product-expansion ladders (only small levels materialized)
    float o2[2] = {ap[1], bm[1]};
    float o4[4], o8[8];
#pragma unroll
    for (int i = 0; i < 2; ++i) { o4[i] = o2[i] * ap[3]; o4[i + 2] = o2[i] * bm[3]; }
#pragma unroll
    for (int i = 0; i < 4; ++i) { o8[i] = o4[i] * ap[5]; o8[i + 4] = o4[i] * bm[5]; }

    float e2[2] = {ap[0], bm[0]};
    float e4[4], e8[8];
#pragma unroll
    for (int i = 0; i < 2; ++i) { e4[i] = e2[i] * ap[2]; e4[i + 2] = e2[i] * bm[2]; }
#pragma unroll
    for (int i = 0; i < 4; ++i) { e8[i] = e4[i] * ap[4]; e8[i + 4] = e4[i] * bm[4]; }

    float G0 = 0.0f, G1 = 0.0f, G2 = 0.0f, G3 = 0.0f;
    float G4 = 0.0f, G5 = 0.0f, G6 = 0.0f, G7 = 0.0f;
#pragma unroll
    for (int i = 0; i < 2; ++i)
        G0 += o2[i] * (ap[2] * tab[0 + i] + bm[2] * tab[2 + i]);
#pragma unroll
    for (int i = 0; i < 4; ++i) {
        G1 += e4[i] * (ap[3] * tab[4 + i]  + bm[3] * tab[8 + i]);
        G2 += o4[i] * (ap[4] * tab[12 + i] + bm[4] * tab[16 + i]);
    }
#pragma unroll
    for (int i = 0; i < 8; ++i) {
        G3 += e8[i] * (ap[5] * tab[20 + i]  + bm[5] * tab[28 + i]);
        G4 += o8[i] * (ap[6] * tab[36 + i]  + bm[6] * tab[44 + i]);
        G5 += e8[i] * (ap[6] * (ap[7] * tab[52 + i] + bm[7] * tab[68 + i])
                     + bm[6] * (ap[7] * tab[60 + i] + bm[7] * tab[76 + i]));
        G6 += o8[i] * (ap[7] * tab[84 + i]  + bm[7] * tab[92 + i]);
        G7 += e8[i] * (ap[6] * tab[100 + i] + bm[6] * tab[108 + i]);
    }

    // ---- S_q cos prefactors ----
    const float c02 = c[0] * c[2], c024 = c02 * c[4], c0246 = c024 * c[6];
    const float c13 = c[1] * c[3], c135 = c13 * c[5], c1357 = c135 * c[7];

    float4 r0, r1;
    r0.x = c[0]  * G0;  r0.y = c[1]  * G1;  r0.z = c02   * G2;  r0.w = c13   * G3;
    r1.x = c024  * G4;  r1.y = c135  * G5;  r1.z = c0246 * G6;  r1.w = c1357 * G7;

    float4* o4p = (float4*)out + (size_t)e * 2;
    o4p[0] = r0;
    o4p[1] = r1;
}

extern "C" void kernel_launch(void* const* d_in, const int* in_sizes, int n_in,
                              void* d_out, int out_size, void* d_ws, size_t ws_size,
                              hipStream_t stream) {
    const float* inputs  = (const float*)d_in[0];
    const float* weights = (const float*)d_in[1];
    float* out = (float*)d_out;
    const int B = in_sizes[0] / 8;             // 32768
    hipLaunchKernelGGL(vqc_kernel, dim3(B / 256), dim3(256), 0, stream,
                       inputs, weights, out);
}

// Round 11
// 59.297 us; speedup vs baseline: 1.1957x; 1.1957x over previous
//
#include <hip/hip_runtime.h>

// 8-qubit VQC — closed-form evaluation (math validated R7-R10), single kernel.
// <Z_q> = Π_{p∈S_q} cos x_p · Σ_b tab_q[b] Π_{p∈V_q\S_q} (1+(-1)^{b_p} sin x_p)
// tab_q[b] = 2^{-|V_q|} Σ_{S-bits} cos Δ_q  (116 floats, weights-only; static
// per-q template descriptors -> all immediates, computed per block into LDS).
// R11 = R9 structure + R10's folded dots, WITHOUT the __launch_bounds__(256,8)
// occupancy pin: R10's pin forced VGPR=32 -> scratch spills (FETCH 4.76 MB vs
// 1.06 MB input, cold dispatch 125 µs). Plain (256) lets the allocator use
// ~64-96 VGPRs, no spill (R9 proved this tier runs the fastest: 58.6 µs).

template<int Q> struct QD;
template<> struct QD<0> { static constexpr int NB=2,NS=1,NA=2;
  static constexpr int vms[2]={1,2}; static constexpr int vis[1]={0};
  static constexpr int mask[2]={3,5}; static constexpr int aidx[2]={0,8}; };
template<> struct QD<1> { static constexpr int NB=3,NS=1,NA=3;
  static constexpr int vms[3]={0,2,3}; static constexpr int vis[1]={1};
  static constexpr int mask[3]={3,6,10}; static constexpr int aidx[3]={0,1,9}; };
template<> struct QD<2> { static constexpr int NB=3,NS=2,NA=4;
  static constexpr int vms[3]={1,3,4}; static constexpr int vis[2]={0,2};
  static constexpr int mask[4]={3,6,12,20}; static constexpr int aidx[4]={0,1,2,10}; };
template<> struct QD<3> { static constexpr int NB=4,NS=2,NA=5;
  static constexpr int vms[4]={0,2,4,5}; static constexpr int vis[2]={1,3};
  static constexpr int mask[5]={3,6,12,24,40}; static constexpr int aidx[5]={0,1,2,3,11}; };
template<> struct QD<4> { static constexpr int NB=4,NS=3,NA=6;
  static constexpr int vms[4]={1,3,5,6}; static constexpr int vis[3]={0,2,4};
  static constexpr int mask[6]={3,6,12,24,48,80}; static constexpr int aidx[6]={0,1,2,3,4,12}; };
template<> struct QD<5> { static constexpr int NB=5,NS=3,NA=7;
  static constexpr int vms[5]={0,2,4,6,7}; static constexpr int vis[3]={1,3,5};
  static constexpr int mask[7]={3,6,12,24,48,96,160}; static constexpr int aidx[7]={0,1,2,3,4,5,13}; };
template<> struct QD<6> { static constexpr int NB=4,NS=4,NA=8;
  static constexpr int vms[4]={1,3,5,7}; static constexpr int vis[4]={0,2,4,6};
  static constexpr int mask[8]={3,6,12,24,48,96,192,64}; static constexpr int aidx[8]={0,1,2,3,4,5,6,14}; };
template<> struct QD<7> { static constexpr int NB=4,NS=4,NA=9;
  static constexpr int vms[4]={0,2,4,6}; static constexpr int vis[4]={1,3,5,7};
  static constexpr int mask[9]={3,6,12,24,48,96,192,128,128}; static constexpr int aidx[9]={0,1,2,3,4,5,6,7,15}; };

template<int Q>
__device__ __forceinline__ float table_entry(int b, const float* wv) {
    using D = QD<Q>;
    int ybase = 0;
#pragma unroll
    for (int k = 0; k < D::NB; ++k) ybase |= ((b >> k) & 1) << D::vms[k];
    float acc = 0.0f;
#pragma unroll
    for (int ys = 0; ys < (1 << D::NS); ++ys) {
        int y = ybase;
#pragma unroll
        for (int k = 0; k < D::NS; ++k) y |= ((ys >> k) & 1) << D::vis[k];
        float d = 0.0f;
#pragma unroll
        for (int j = 0; j < D::NA; ++j)
            d += (__popc(y & D::mask[j]) & 1) ? -wv[D::aidx[j]] : wv[D::aidx[j]];
        acc += __cosf(d);
    }
    return acc * (1.0f / (float)(1 << (D::NS + D::NB)));
}

__global__ __launch_bounds__(256) void vqc_kernel(
    const float* __restrict__ inputs,   // (B, 8)
    const float* __restrict__ weights,  // (2, 8)
    float* __restrict__ out)            // (B, 8)
{
    __shared__ float tab[116];
    const int t = threadIdx.x;

    // ---- phase 1: weights-only table into LDS (threads 0..115, all static) ----
    if (t < 116) {
        float wv[16];
#pragma unroll
        for (int j = 0; j < 16; ++j) wv[j] = weights[j];
        float val;
        if      (t <   4) val = table_entry<0>(t,       wv);
        else if (t <  12) val = table_entry<1>(t -   4, wv);
        else if (t <  20) val = table_entry<2>(t -  12, wv);
        else if (t <  36) val = table_entry<3>(t -  20, wv);
        else if (t <  52) val = table_entry<4>(t -  36, wv);
        else if (t <  84) val = table_entry<5>(t -  52, wv);
        else if (t < 100) val = table_entry<6>(t -  84, wv);
        else              val = table_entry<7>(t - 100, wv);
        tab[t] = val;
    }
    __syncthreads();

    // ---- phase 2: per-element closed form, expansions folded into dots ----
    const int e = blockIdx.x * 256 + t;

    const float4* i4 = (const float4*)inputs + (size_t)e * 2;
    const float4 A = i4[0], Bv = i4[1];
    const float x[8] = {A.x, A.y, A.z, A.w, Bv.x, Bv.y, Bv.z, Bv.w};

    float s[8], c[8], ap[8], bm[8];
#pragma unroll
    for (int p = 0; p < 8; ++p) {
        s[p] = __sinf(x[p]);
        c[p] = __cosf(x[p]);
        ap[p] = 1.0f + s[p];
        bm[p] = 1.0f - s[p];
    }

    // product-expansion ladders (only small levels materialized)
    float o2[2] = {ap[1], bm[1]};
    float o4[4], o8[8];
#pragma unroll
    for (int i = 0; i < 2; ++i) { o4[i] = o2[i] * ap[3]; o4[i + 2] = o2[i] * bm[3]; }
#pragma unroll
    for (int i = 0; i < 4; ++i) { o8[i] = o4[i] * ap[5]; o8[i + 4] = o4[i] * bm[5]; }

    float e2[2] = {ap[0], bm[0]};
    float e4[4], e8[8];
#pragma unroll
    for (int i = 0; i < 2; ++i) { e4[i] = e2[i] * ap[2]; e4[i + 2] = e2[i] * bm[2]; }
#pragma unroll
    for (int i = 0; i < 4; ++i) { e8[i] = e4[i] * ap[4]; e8[i + 4] = e4[i] * bm[4]; }

    float G0 = 0.0f, G1 = 0.0f, G2 = 0.0f, G3 = 0.0f;
    float G4 = 0.0f, G5 = 0.0f, G6 = 0.0f, G7 = 0.0f;
#pragma unroll
    for (int i = 0; i < 2; ++i)
        G0 += o2[i] * (ap[2] * tab[0 + i] + bm[2] * tab[2 + i]);
#pragma unroll
    for (int i = 0; i < 4; ++i) {
        G1 += e4[i] * (ap[3] * tab[4 + i]  + bm[3] * tab[8 + i]);
        G2 += o4[i] * (ap[4] * tab[12 + i] + bm[4] * tab[16 + i]);
    }
#pragma unroll
    for (int i = 0; i < 8; ++i) {
        G3 += e8[i] * (ap[5] * tab[20 + i]  + bm[5] * tab[28 + i]);
        G4 += o8[i] * (ap[6] * tab[36 + i]  + bm[6] * tab[44 + i]);
        G5 += e8[i] * (ap[6] * (ap[7] * tab[52 + i] + bm[7] * tab[68 + i])
                     + bm[6] * (ap[7] * tab[60 + i] + bm[7] * tab[76 + i]));
        G6 += o8[i] * (ap[7] * tab[84 + i]  + bm[7] * tab[92 + i]);
        G7 += e8[i] * (ap[6] * tab[100 + i] + bm[6] * tab[108 + i]);
    }

    // ---- S_q cos prefactors ----
    const float c02 = c[0] * c[2], c024 = c02 * c[4], c0246 = c024 * c[6];
    const float c13 = c[1] * c[3], c135 = c13 * c[5], c1357 = c135 * c[7];

    float4 r0, r1;
    r0.x = c[0]  * G0;  r0.y = c[1]  * G1;  r0.z = c02   * G2;  r0.w = c13   * G3;
    r1.x = c024  * G4;  r1.y = c135  * G5;  r1.z = c0246 * G6;  r1.w = c1357 * G7;

    float4* o4p = (float4*)out + (size_t)e * 2;
    o4p[0] = r0;
    o4p[1] = r1;
}

extern "C" void kernel_launch(void* const* d_in, const int* in_sizes, int n_in,
                              void* d_out, int out_size, void* d_ws, size_t ws_size,
                              hipStream_t stream) {
    const float* inputs  = (const float*)d_in[0];
    const float* weights = (const float*)d_in[1];
    float* out = (float*)d_out;
    const int B = in_sizes[0] / 8;             // 32768
    hipLaunchKernelGGL(vqc_kernel, dim3(B / 256), dim3(256), 0, stream,
                       inputs, weights, out);
}